// Round 12
// baseline (131.027 us; speedup 1.0000x reference)
//
#include <hip/hip_runtime.h>
#include <math.h>

// RelativeAttention on MI355X (gfx950). FP32 inputs/output; bf16 intermediates, fp32 accum.
// Round 12: attn = BARRIER-FREE per-wave async-LDS pipeline. Each wave owns private K/V
// double-buffers, stages chunk c+1 via global_load_lds (un-sinkable), and syncs with
// s_waitcnt vmcnt(4) (in-order retirement => buffer c done; conservative under compiler
// loads). GEMMs switch to async_cp16 staging (m97 pattern) + R11 XOR swizzle.
// B=8, C=256, H=W=32 (L=1024), nh=8, dk=dv=32, OUT_C=256.

typedef unsigned short u16;
typedef __bf16 bf16;
typedef bf16 bf16x8 __attribute__((ext_vector_type(8)));
typedef bf16 bf16x4 __attribute__((ext_vector_type(4)));
typedef short s16x4 __attribute__((ext_vector_type(4)));
typedef float f32x4 __attribute__((ext_vector_type(4)));
typedef float f32x4u __attribute__((ext_vector_type(4), aligned(4)));
typedef u16 u16x8 __attribute__((ext_vector_type(8)));
typedef u16 u16x4 __attribute__((ext_vector_type(4)));

#define DEVI __device__ __forceinline__

DEVI u16 bfbits(float f) { return __builtin_bit_cast(u16, (bf16)f); }

DEVI void async_cp16(const u16* g, u16* l) {
    __builtin_amdgcn_global_load_lds((const __attribute__((address_space(1))) void*)g,
                                     (__attribute__((address_space(3))) void*)l, 16, 0, 0);
}

// 16x16x16 bf16 MFMA (K=16): A[m=lane&15][k=quad*4+j], B[k=quad*4+j][n=lane&15],
// C/D[row=quad*4+reg][col=lane&15]. (absmax-verified R7-R11.)
DEVI f32x4 pv_mfma(bf16x4 a, bf16x4 b, f32x4 c) {
#if __has_builtin(__builtin_amdgcn_mfma_f32_16x16x16bf16_1k)
    return __builtin_amdgcn_mfma_f32_16x16x16bf16_1k(
        __builtin_bit_cast(s16x4, a), __builtin_bit_cast(s16x4, b), c, 0, 0, 0);
#else
    asm("s_nop 1\n\tv_mfma_f32_16x16x16_bf16 %0, %1, %2, %0"
        : "+v"(c) : "v"(a), "v"(b));
    return c;
#endif
}

// ---------------- fused prep: transposes + bias prescale ----------------
__global__ __launch_bounds__(256) void prep(const float* __restrict__ X,
                                            const float* __restrict__ Qw, const float* __restrict__ Kw,
                                            const float* __restrict__ Vw, const float* __restrict__ Fw,
                                            const float* __restrict__ RB,
                                            u16* __restrict__ XF, u16* __restrict__ WT,
                                            float* __restrict__ RBs) {
    __shared__ u16 t[64 * 65];
    const int blk = blockIdx.x, tid = threadIdx.x;
    if (blk < 576) {
        const float* src;
        int cbase, rbase, rows_total;
        u16* dst;
        if (blk < 512) {
            const int b = blk >> 6;
            cbase = (blk & 3) * 64; rbase = ((blk >> 2) & 15) * 64;
            src = X + (size_t)b * 256 * 1024; dst = XF + (size_t)b * 1024 * 256;
            rows_total = 1024;
        } else {
            const int t2 = blk - 512, wsel = t2 >> 4;
            cbase = (t2 & 3) * 64; rbase = ((t2 >> 2) & 3) * 64;
            src = wsel == 0 ? Qw : wsel == 1 ? Kw : wsel == 2 ? Vw : Fw;
            dst = WT + (size_t)wsel * 256 * 256;
            rows_total = 256;
        }
        const int w = tid >> 6, r = tid & 63;
#pragma unroll
        for (int i = 0; i < 16; i++) {
            const int c = w * 16 + i;
            t[c * 65 + r] = bfbits(src[(size_t)(cbase + c) * rows_total + rbase + r]);
        }
        __syncthreads();
#pragma unroll
        for (int i = 0; i < 2; i++) {
            const int idx = i * 256 + tid;
            const int r2 = idx >> 3, cg = idx & 7;
            u16x8 v;
#pragma unroll
            for (int j = 0; j < 8; j++) v[j] = t[(cg * 8 + j) * 65 + r2];
            *(u16x8*)&dst[(size_t)(rbase + r2) * 256 + cbase + cg * 8] = v;
        }
    } else {
        const int n = 8 * 3969;
        for (int i = (blk - 576) * 256 + tid; i < n; i += 32 * 256)
            RBs[i] = RB[i] * 1.44269504f;
    }
}

// ---------------- unified GEMM: D[m][n] = sum_k A[m][k]*Bt[n][k], K=256, bf16 in ----------------
// 64x64 tile, BK=32, 4 waves each 32x32. m97 2-barrier K-loop with async_cp16 staging
// (one DMA per thread per matrix per tile) + XOR-swizzled chunk columns (conflict-free b128).
__global__ __launch_bounds__(256, 6) void gemm_fused(const u16* __restrict__ xf, const u16* __restrict__ wt,
                                                     u16* __restrict__ q, u16* __restrict__ kk,
                                                     u16* __restrict__ vt, const u16* __restrict__ ob,
                                                     float* __restrict__ outf, const float* __restrict__ ffb,
                                                     int base_mode) {
    __shared__ __align__(16) u16 lA[64 * 32];
    __shared__ __align__(16) u16 lB[64 * 32];
    const int tid = threadIdx.x;
    const int wave = tid >> 6, lane = tid & 63;
    const int quad = lane >> 4, l15 = lane & 15;

    int mode, mbase, nbase;
    const u16 *A, *Bt;
    if (base_mode == 2) {
        mode = 2; A = wt + 768 * 256; Bt = ob;               // M=256, N=8192
        mbase = (blockIdx.x & 3) * 64; nbase = (blockIdx.x >> 2) * 64;
    } else if (blockIdx.x < 1024) {
        mode = 0; A = xf; Bt = wt;                            // M=8192, N=512
        mbase = (blockIdx.x >> 3) * 64; nbase = (blockIdx.x & 7) * 64;
    } else {
        mode = 1; A = wt + 512 * 256; Bt = xf;                // M=256, N=8192
        const int t = blockIdx.x - 1024;
        mbase = (t & 3) * 64; nbase = (t >> 2) * 64;
    }

    const int m0 = (wave >> 1) * 32, n0 = (wave & 1) * 32;
    // staging: thread covers LDS row srow=tid>>2, chunk col tid&3; swizzled global chunk col
    const int srow = tid >> 2;
    const int sgcol = (lane & 3) ^ ((lane >> 3) & 3);   // (chunk col) ^ ((srow>>1)&3), wave-invariant
    const size_t arow = (size_t)(mbase + srow) * 256 + sgcol * 8;
    const size_t brow = (size_t)(nbase + srow) * 256 + sgcol * 8;
    // readers: row = 16a + l15 -> swz = (l15>>1)&3; chunk = quad^swz
    const int kcol = ((quad ^ ((l15 >> 1) & 3))) * 8;

    f32x4 acc[2][2];
#pragma unroll
    for (int i = 0; i < 2; i++)
#pragma unroll
        for (int j = 0; j < 2; j++) acc[i][j] = f32x4{0.f, 0.f, 0.f, 0.f};

    for (int kb = 0; kb < 256; kb += 32) {
        __syncthreads();   // previous iter's LDS reads done before DMA overwrite
        async_cp16(&A[arow + kb], &lA[wave * 512]);
        async_cp16(&Bt[brow + kb], &lB[wave * 512]);
        __syncthreads();   // compiler drains vmcnt before s_barrier -> staged data visible
        bf16x8 af[2], bfr[2];
#pragma unroll
        for (int i = 0; i < 2; i++) af[i] = *(const bf16x8*)&lA[(m0 + i * 16 + l15) * 32 + kcol];
#pragma unroll
        for (int j = 0; j < 2; j++) bfr[j] = *(const bf16x8*)&lB[(n0 + j * 16 + l15) * 32 + kcol];
#pragma unroll
        for (int i = 0; i < 2; i++)
#pragma unroll
            for (int j = 0; j < 2; j++)
                acc[i][j] = __builtin_amdgcn_mfma_f32_16x16x32_bf16(af[i], bfr[j], acc[i][j], 0, 0, 0);
    }

    // epilogue: C-layout col = lane&15, row = quad*4 + reg
#pragma unroll
    for (int i = 0; i < 2; i++) {
#pragma unroll
        for (int j = 0; j < 2; j++) {
#pragma unroll
            for (int r = 0; r < 4; r++) {
                const int gm = mbase + m0 + i * 16 + quad * 4 + r;
                const int gn = nbase + n0 + j * 16 + l15;
                float v = acc[i][j][r];
                if (mode == 0) {
                    const int b = gm >> 10, l = gm & 1023;
                    int n = gn;
                    u16* dst = q;
                    if (n >= 256) { n -= 256; dst = kk; }
                    else v *= 1.44269504f;                 // fold log2e into q
                    const int h = n >> 5, d = n & 31;
                    dst[(((size_t)(b * 8 + h) * 1024 + l) << 5) + d] = bfbits(v);
                } else if (mode == 1) {
                    const int h = gm >> 5, d = gm & 31;
                    const int b = gn >> 10, l = gn & 1023;
                    vt[(((size_t)(b * 8 + h) * 32 + d) << 10) + l] = bfbits(v);
                } else {
                    const int b = gn >> 10, l = gn & 1023;
                    outf[(((size_t)(b * 256 + gm)) << 10) + l] = v + ffb[gm];
                }
            }
        }
    }
}

// ---------------- flash attention: barrier-free per-wave async pipeline ----------------
// 1024 blocks x 4 waves, fully independent waves. Each wave: private K/V LDS double-buffer
// (8 KB); stage chunk c+1 via 4 global_load_lds; s_waitcnt vmcnt(4) guarantees (in-order
// retirement) buffer c staged; compute c. NO __syncthreads anywhere. XOR-swizzled chunks
// (R11 reader math). S^T = K*Q^T -> bias+exp2 -> P in 16x16x16 A-layout -> 4x PV MFMA.
__global__ __launch_bounds__(256, 4) void attn(const u16* __restrict__ Q, const u16* __restrict__ Kb,
                                               const u16* __restrict__ Vt, const float* __restrict__ RBs,
                                               u16* __restrict__ O) {
    __shared__ __align__(16) u16 kbuf[4][2][32 * 32];   // [wave][buf][key][d], swizzled chunks
    __shared__ __align__(16) u16 vbuf[4][2][32 * 32];   // [wave][buf][d][key], swizzled chunks
    const int tid = threadIdx.x;
    const int wave = tid >> 6, lane = tid & 63;
    const int quad = lane >> 4, l15 = lane & 15;
    const int blk = blockIdx.x;
    const int bh = ((blk >> 7) << 3) + (blk & 7);       // XCD swizzle
    const int qt = (blk >> 3) & 15;
    const int b = bh >> 3, h = bh & 7;
    const int qbase = qt * 64 + wave * 16;
    const size_t bhL = (size_t)bh * 1024;

    const bf16x8 qf = *(const bf16x8*)&Q[(bhL + qbase + l15) * 32 + quad * 8];   // Q[query=l15][d]
    const float* brow0 = RBs + (size_t)h * 3969
                         + (32 - (qbase >> 5)) * 32 + 32 - (qbase & 31) - l15 + quad * 4;
    const int srow = lane >> 2;
    const int sgcol = (lane & 3) ^ ((lane >> 3) & 3);
    const u16* ksrc = &Kb[bhL * 32];
    const u16* vsrc_lo = &Vt[(((size_t)bh * 32) + srow) << 10];
    const u16* vsrc_hi = &Vt[(((size_t)bh * 32) + 16 + srow) << 10];

    float lsum = 0.f;
    f32x4 o_lo{0.f, 0.f, 0.f, 0.f}, o_hi{0.f, 0.f, 0.f, 0.f};

    // reader-side swizzle terms (row-pair XOR)
    const int swz = (l15 >> 1) & 3;
    const int kcol = (quad ^ swz) * 8;
    const int g0 = (2 * ((quad >> 1) ^ swz) + (quad & 1)) * 4;
    const int g1 = (2 * (((quad >> 1) + 2) ^ swz) + (quad & 1)) * 4;

#define STAGE(buf, c) do {                                                              \
        const int kb_ = (c) * 32;                                                       \
        async_cp16(ksrc + kb_ * 32 + srow * 32 + sgcol * 8, &kbuf[wave][buf][0]);       \
        async_cp16(ksrc + kb_ * 32 + 512 + srow * 32 + sgcol * 8, &kbuf[wave][buf][512]); \
        async_cp16(vsrc_lo + kb_ + sgcol * 8, &vbuf[wave][buf][0]);                     \
        async_cp16(vsrc_hi + kb_ + sgcol * 8, &vbuf[wave][buf][512]);                   \
    } while (0)

#define COMPUTE(cur, c) do {                                                              \
        const bf16x8 kf0 = *(const bf16x8*)&kbuf[wave][cur][l15 * 32 + kcol];             \
        const bf16x8 kf1 = *(const bf16x8*)&kbuf[wave][cur][(16 + l15) * 32 + kcol];      \
        const bf16x4 v00 = __builtin_bit_cast(bf16x4, *(const u16x4*)&vbuf[wave][cur][l15 * 32 + g0]); \
        const bf16x4 v10 = __builtin_bit_cast(bf16x4, *(const u16x4*)&vbuf[wave][cur][l15 * 32 + g1]); \
        const bf16x4 v01 = __builtin_bit_cast(bf16x4, *(const u16x4*)&vbuf[wave][cur][(16 + l15) * 32 + g0]); \
        const bf16x4 v11 = __builtin_bit_cast(bf16x4, *(const u16x4*)&vbuf[wave][cur][(16 + l15) * 32 + g1]); \
        const f32x4u b0 = *(const f32x4u*)(brow0 + (c) * 32);                             \
        const f32x4u b1 = *(const f32x4u*)(brow0 + (c) * 32 + 16);                        \
        const f32x4 z{0.f, 0.f, 0.f, 0.f};                                                \
        f32x4 s0 = __builtin_amdgcn_mfma_f32_16x16x32_bf16(kf0, qf, z, 0, 0, 0);          \
        f32x4 s1 = __builtin_amdgcn_mfma_f32_16x16x32_bf16(kf1, qf, z, 0, 0, 0);          \
        bf16x4 p0, p1;                                                                    \
        _Pragma("unroll")                                                                 \
        for (int r = 0; r < 4; r++) {                                                     \
            const float e0 = exp2f(s0[r] + b0[r]);                                        \
            const float e1 = exp2f(s1[r] + b1[r]);                                        \
            lsum += e0 + e1;                                                              \
            p0[r] = (bf16)e0;                                                             \
            p1[r] = (bf16)e1;                                                             \
        }                                                                                 \
        o_lo = pv_mfma(p0, v00, o_lo);                                                    \
        o_hi = pv_mfma(p0, v01, o_hi);                                                    \
        o_lo = pv_mfma(p1, v10, o_lo);                                                    \
        o_hi = pv_mfma(p1, v11, o_hi);                                                    \
    } while (0)

    STAGE(0, 0);
    for (int c = 0; c < 31; c++) {
        STAGE((c + 1) & 1, c + 1);                           // double-buffer prefetch
        // in-order vmcnt retirement: <=4 outstanding => buffer c's 4 loads retired.
        // Compiler-interleaved loads only make this conservative, never unsafe.
        asm volatile("s_waitcnt vmcnt(4)" ::: "memory");
        COMPUTE(c & 1, c);
    }
    asm volatile("s_waitcnt vmcnt(0)" ::: "memory");
    COMPUTE(1, 31);
#undef STAGE
#undef COMPUTE

    // lsum on lane = partial row-sum for query l15; finish across quads
    lsum += __shfl_xor(lsum, 16);
    lsum += __shfl_xor(lsum, 32);
#pragma unroll
    for (int r = 0; r < 4; r++) {
        const float inv = 1.f / __shfl(lsum, quad * 4 + r);
        const int i = qbase + quad * 4 + r;
        O[((size_t)(b * 1024 + i) * 256) + h * 32 + l15] = bfbits(o_lo[r] * inv);
        O[((size_t)(b * 1024 + i) * 256) + h * 32 + 16 + l15] = bfbits(o_hi[r] * inv);
    }
}

extern "C" void kernel_launch(void* const* d_in, const int* in_sizes, int n_in,
                              void* d_out, int out_size, void* d_ws, size_t ws_size,
                              hipStream_t stream) {
    const float* x   = (const float*)d_in[0];
    const float* Qw  = (const float*)d_in[1];
    const float* Kw  = (const float*)d_in[2];
    const float* Vw  = (const float*)d_in[3];
    const float* Fw  = (const float*)d_in[4];
    const float* ffb = (const float*)d_in[5];
    const float* RB  = (const float*)d_in[6];
    // d_in[7] = rel_idx (int32): deterministic, computed analytically in-kernel.

    u16* ws = (u16*)d_ws;
    u16* xf = ws;                   // 8192 x 256 bf16 (4 MB)   ... later reused as ob
    u16* wt = xf + 2097152;         // 1024 x 256 bf16 (0.5 MB) [Qw^T|Kw^T|Vw^T|ffw^T]
    u16* q  = wt + 262144;          // (b,h,l,d)  bf16 (4 MB), pre-scaled by log2e
    u16* kk = q  + 2097152;         // (b,h,l,d)  bf16 (4 MB)
    u16* vt = kk + 2097152;         // (b,h,d,l)  bf16 (4 MB)
    float* RBs = (float*)(vt + 2097152);   // 8 x 3969 fp32 (127 KB), bias * log2e
    u16* ob = xf;                   // (b,l,h*32+d) bf16 — aliases xf (dead after V proj)

    prep<<<dim3(608), 256, 0, stream>>>(x, Qw, Kw, Vw, Fw, RB, xf, wt, RBs);
    gemm_fused<<<dim3(1536), 256, 0, stream>>>(xf, wt, q, kk, vt, nullptr, nullptr, nullptr, 0); // QK + V^T
    attn<<<dim3(1024), 256, 0, stream>>>(q, kk, vt, RBs, ob);
    gemm_fused<<<dim3(512), 256, 0, stream>>>(xf, wt, q, kk, vt, ob, (float*)d_out, ffb, 2);     // FF
}

// Round 14
// 124.626 us; speedup vs baseline: 1.0514x; 1.0514x over previous
//
#include <hip/hip_runtime.h>
#include <math.h>

// RelativeAttention on MI355X (gfx950). FP32 inputs/output; bf16 intermediates, fp32 accum.
// Round 14: R13's depth-2 barrier-free pipeline + the race fix: s_waitcnt lgkmcnt(0) before
// each STAGE that overwrites a just-read buffer (ds_reads guaranteed executed before the DMA
// can land — closes the replay-only corruption). GEMMs: async_cp16 + XOR swizzle (R12).
// B=8, C=256, H=W=32 (L=1024), nh=8, dk=dv=32, OUT_C=256.

typedef unsigned short u16;
typedef __bf16 bf16;
typedef bf16 bf16x8 __attribute__((ext_vector_type(8)));
typedef bf16 bf16x4 __attribute__((ext_vector_type(4)));
typedef short s16x4 __attribute__((ext_vector_type(4)));
typedef float f32x4 __attribute__((ext_vector_type(4)));
typedef float f32x4u __attribute__((ext_vector_type(4), aligned(4)));
typedef u16 u16x8 __attribute__((ext_vector_type(8)));
typedef u16 u16x4 __attribute__((ext_vector_type(4)));

#define DEVI __device__ __forceinline__

DEVI u16 bfbits(float f) { return __builtin_bit_cast(u16, (bf16)f); }

DEVI void async_cp16(const u16* g, u16* l) {
    __builtin_amdgcn_global_load_lds((const __attribute__((address_space(1))) void*)g,
                                     (__attribute__((address_space(3))) void*)l, 16, 0, 0);
}

// 16x16x16 bf16 MFMA (K=16): A[m=lane&15][k=quad*4+j], B[k=quad*4+j][n=lane&15],
// C/D[row=quad*4+reg][col=lane&15]. (absmax-verified R7-R13.)
DEVI f32x4 pv_mfma(bf16x4 a, bf16x4 b, f32x4 c) {
#if __has_builtin(__builtin_amdgcn_mfma_f32_16x16x16bf16_1k)
    return __builtin_amdgcn_mfma_f32_16x16x16bf16_1k(
        __builtin_bit_cast(s16x4, a), __builtin_bit_cast(s16x4, b), c, 0, 0, 0);
#else
    asm("s_nop 1\n\tv_mfma_f32_16x16x16_bf16 %0, %1, %2, %0"
        : "+v"(c) : "v"(a), "v"(b));
    return c;
#endif
}

// ---------------- fused prep: transposes + bias prescale ----------------
__global__ __launch_bounds__(256) void prep(const float* __restrict__ X,
                                            const float* __restrict__ Qw, const float* __restrict__ Kw,
                                            const float* __restrict__ Vw, const float* __restrict__ Fw,
                                            const float* __restrict__ RB,
                                            u16* __restrict__ XF, u16* __restrict__ WT,
                                            float* __restrict__ RBs) {
    __shared__ u16 t[64 * 65];
    const int blk = blockIdx.x, tid = threadIdx.x;
    if (blk < 576) {
        const float* src;
        int cbase, rbase, rows_total;
        u16* dst;
        if (blk < 512) {
            const int b = blk >> 6;
            cbase = (blk & 3) * 64; rbase = ((blk >> 2) & 15) * 64;
            src = X + (size_t)b * 256 * 1024; dst = XF + (size_t)b * 1024 * 256;
            rows_total = 1024;
        } else {
            const int t2 = blk - 512, wsel = t2 >> 4;
            cbase = (t2 & 3) * 64; rbase = ((t2 >> 2) & 3) * 64;
            src = wsel == 0 ? Qw : wsel == 1 ? Kw : wsel == 2 ? Vw : Fw;
            dst = WT + (size_t)wsel * 256 * 256;
            rows_total = 256;
        }
        const int w = tid >> 6, r = tid & 63;
#pragma unroll
        for (int i = 0; i < 16; i++) {
            const int c = w * 16 + i;
            t[c * 65 + r] = bfbits(src[(size_t)(cbase + c) * rows_total + rbase + r]);
        }
        __syncthreads();
#pragma unroll
        for (int i = 0; i < 2; i++) {
            const int idx = i * 256 + tid;
            const int r2 = idx >> 3, cg = idx & 7;
            u16x8 v;
#pragma unroll
            for (int j = 0; j < 8; j++) v[j] = t[(cg * 8 + j) * 65 + r2];
            *(u16x8*)&dst[(size_t)(rbase + r2) * 256 + cbase + cg * 8] = v;
        }
    } else {
        const int n = 8 * 3969;
        for (int i = (blk - 576) * 256 + tid; i < n; i += 32 * 256)
            RBs[i] = RB[i] * 1.44269504f;
    }
}

// ---------------- unified GEMM: D[m][n] = sum_k A[m][k]*Bt[n][k], K=256, bf16 in ----------------
// 64x64 tile, BK=32, 4 waves each 32x32. async_cp16 staging + XOR-swizzled chunks.
__global__ __launch_bounds__(256, 6) void gemm_fused(const u16* __restrict__ xf, const u16* __restrict__ wt,
                                                     u16* __restrict__ q, u16* __restrict__ kk,
                                                     u16* __restrict__ vt, const u16* __restrict__ ob,
                                                     float* __restrict__ outf, const float* __restrict__ ffb,
                                                     int base_mode) {
    __shared__ __align__(16) u16 lA[64 * 32];
    __shared__ __align__(16) u16 lB[64 * 32];
    const int tid = threadIdx.x;
    const int wave = tid >> 6, lane = tid & 63;
    const int quad = lane >> 4, l15 = lane & 15;

    int mode, mbase, nbase;
    const u16 *A, *Bt;
    if (base_mode == 2) {
        mode = 2; A = wt + 768 * 256; Bt = ob;               // M=256, N=8192
        mbase = (blockIdx.x & 3) * 64; nbase = (blockIdx.x >> 2) * 64;
    } else if (blockIdx.x < 1024) {
        mode = 0; A = xf; Bt = wt;                            // M=8192, N=512
        mbase = (blockIdx.x >> 3) * 64; nbase = (blockIdx.x & 7) * 64;
    } else {
        mode = 1; A = wt + 512 * 256; Bt = xf;                // M=256, N=8192
        const int t = blockIdx.x - 1024;
        mbase = (t & 3) * 64; nbase = (t >> 2) * 64;
    }

    const int m0 = (wave >> 1) * 32, n0 = (wave & 1) * 32;
    const int srow = tid >> 2;
    const int sgcol = (lane & 3) ^ ((lane >> 3) & 3);
    const size_t arow = (size_t)(mbase + srow) * 256 + sgcol * 8;
    const size_t brow = (size_t)(nbase + srow) * 256 + sgcol * 8;
    const int kcol = ((quad ^ ((l15 >> 1) & 3))) * 8;

    f32x4 acc[2][2];
#pragma unroll
    for (int i = 0; i < 2; i++)
#pragma unroll
        for (int j = 0; j < 2; j++) acc[i][j] = f32x4{0.f, 0.f, 0.f, 0.f};

    for (int kb = 0; kb < 256; kb += 32) {
        __syncthreads();
        async_cp16(&A[arow + kb], &lA[wave * 512]);
        async_cp16(&Bt[brow + kb], &lB[wave * 512]);
        __syncthreads();
        bf16x8 af[2], bfr[2];
#pragma unroll
        for (int i = 0; i < 2; i++) af[i] = *(const bf16x8*)&lA[(m0 + i * 16 + l15) * 32 + kcol];
#pragma unroll
        for (int j = 0; j < 2; j++) bfr[j] = *(const bf16x8*)&lB[(n0 + j * 16 + l15) * 32 + kcol];
#pragma unroll
        for (int i = 0; i < 2; i++)
#pragma unroll
            for (int j = 0; j < 2; j++)
                acc[i][j] = __builtin_amdgcn_mfma_f32_16x16x32_bf16(af[i], bfr[j], acc[i][j], 0, 0, 0);
    }

    // epilogue: C-layout col = lane&15, row = quad*4 + reg
#pragma unroll
    for (int i = 0; i < 2; i++) {
#pragma unroll
        for (int j = 0; j < 2; j++) {
#pragma unroll
            for (int r = 0; r < 4; r++) {
                const int gm = mbase + m0 + i * 16 + quad * 4 + r;
                const int gn = nbase + n0 + j * 16 + l15;
                float v = acc[i][j][r];
                if (mode == 0) {
                    const int b = gm >> 10, l = gm & 1023;
                    int n = gn;
                    u16* dst = q;
                    if (n >= 256) { n -= 256; dst = kk; }
                    else v *= 1.44269504f;                 // fold log2e into q
                    const int h = n >> 5, d = n & 31;
                    dst[(((size_t)(b * 8 + h) * 1024 + l) << 5) + d] = bfbits(v);
                } else if (mode == 1) {
                    const int h = gm >> 5, d = gm & 31;
                    const int b = gn >> 10, l = gn & 1023;
                    vt[(((size_t)(b * 8 + h) * 32 + d) << 10) + l] = bfbits(v);
                } else {
                    const int b = gn >> 10, l = gn & 1023;
                    outf[(((size_t)(b * 256 + gm)) << 10) + l] = v + ffb[gm];
                }
            }
        }
    }
}

// ---------------- flash attention: barrier-free per-wave async pipeline, depth-2, race-fixed --
// 1024 blocks x 4 independent waves. Per-wave private K/V LDS double-buffers (8 KB), XOR
// swizzle. STAGE(buf) issued AFTER the COMPUTE(buf) that frees it (stage->use ~2 chunks >
// L2 latency) — with an lgkmcnt(0) drain first so the buffer's ds_reads have EXECUTED before
// the DMA can overwrite (fixes R13's replay-only corruption). vmcnt(4) = oldest-4 retired.
__global__ __launch_bounds__(256, 4) void attn(const u16* __restrict__ Q, const u16* __restrict__ Kb,
                                               const u16* __restrict__ Vt, const float* __restrict__ RBs,
                                               u16* __restrict__ O) {
    __shared__ __align__(16) u16 kbuf[4][2][32 * 32];   // [wave][buf][key][d], swizzled chunks
    __shared__ __align__(16) u16 vbuf[4][2][32 * 32];   // [wave][buf][d][key], swizzled chunks
    const int tid = threadIdx.x;
    const int wave = tid >> 6, lane = tid & 63;
    const int quad = lane >> 4, l15 = lane & 15;
    const int blk = blockIdx.x;
    const int bh = ((blk >> 7) << 3) + (blk & 7);       // XCD swizzle
    const int qt = (blk >> 3) & 15;
    const int b = bh >> 3, h = bh & 7;
    const int qbase = qt * 64 + wave * 16;
    const size_t bhL = (size_t)bh * 1024;

    const bf16x8 qf = *(const bf16x8*)&Q[(bhL + qbase + l15) * 32 + quad * 8];   // Q[query=l15][d]
    const float* brow0 = RBs + (size_t)h * 3969
                         + (32 - (qbase >> 5)) * 32 + 32 - (qbase & 31) - l15 + quad * 4;
    const int srow = lane >> 2;
    const int sgcol = (lane & 3) ^ ((lane >> 3) & 3);
    const u16* ksrc = &Kb[bhL * 32];
    const u16* vsrc_lo = &Vt[(((size_t)bh * 32) + srow) << 10];
    const u16* vsrc_hi = &Vt[(((size_t)bh * 32) + 16 + srow) << 10];

    float lsum = 0.f;
    f32x4 o_lo{0.f, 0.f, 0.f, 0.f}, o_hi{0.f, 0.f, 0.f, 0.f};

    // reader-side swizzle terms (row-pair XOR)
    const int swz = (l15 >> 1) & 3;
    const int kcol = (quad ^ swz) * 8;
    const int g0 = (2 * ((quad >> 1) ^ swz) + (quad & 1)) * 4;
    const int g1 = (2 * (((quad >> 1) + 2) ^ swz) + (quad & 1)) * 4;

#define STAGE(buf, c) do {                                                              \
        const int kb_ = (c) * 32;                                                       \
        async_cp16(ksrc + kb_ * 32 + srow * 32 + sgcol * 8, &kbuf[wave][buf][0]);       \
        async_cp16(ksrc + kb_ * 32 + 512 + srow * 32 + sgcol * 8, &kbuf[wave][buf][512]); \
        async_cp16(vsrc_lo + kb_ + sgcol * 8, &vbuf[wave][buf][0]);                     \
        async_cp16(vsrc_hi + kb_ + sgcol * 8, &vbuf[wave][buf][512]);                   \
    } while (0)

#define COMPUTE(cur, c) do {                                                              \
        const bf16x8 kf0 = *(const bf16x8*)&kbuf[wave][cur][l15 * 32 + kcol];             \
        const bf16x8 kf1 = *(const bf16x8*)&kbuf[wave][cur][(16 + l15) * 32 + kcol];      \
        const bf16x4 v00 = __builtin_bit_cast(bf16x4, *(const u16x4*)&vbuf[wave][cur][l15 * 32 + g0]); \
        const bf16x4 v10 = __builtin_bit_cast(bf16x4, *(const u16x4*)&vbuf[wave][cur][l15 * 32 + g1]); \
        const bf16x4 v01 = __builtin_bit_cast(bf16x4, *(const u16x4*)&vbuf[wave][cur][(16 + l15) * 32 + g0]); \
        const bf16x4 v11 = __builtin_bit_cast(bf16x4, *(const u16x4*)&vbuf[wave][cur][(16 + l15) * 32 + g1]); \
        const f32x4u b0 = *(const f32x4u*)(brow0 + (c) * 32);                             \
        const f32x4u b1 = *(const f32x4u*)(brow0 + (c) * 32 + 16);                        \
        const f32x4 z{0.f, 0.f, 0.f, 0.f};                                                \
        f32x4 s0 = __builtin_amdgcn_mfma_f32_16x16x32_bf16(kf0, qf, z, 0, 0, 0);          \
        f32x4 s1 = __builtin_amdgcn_mfma_f32_16x16x32_bf16(kf1, qf, z, 0, 0, 0);          \
        bf16x4 p0, p1;                                                                    \
        float ls0 = 0.f, ls1 = 0.f;                                                       \
        _Pragma("unroll")                                                                 \
        for (int r = 0; r < 4; r++) {                                                     \
            const float e0 = __builtin_amdgcn_exp2f(s0[r] + b0[r]);                       \
            const float e1 = __builtin_amdgcn_exp2f(s1[r] + b1[r]);                       \
            ls0 += e0; ls1 += e1;                                                         \
            p0[r] = (bf16)e0;                                                             \
            p1[r] = (bf16)e1;                                                             \
        }                                                                                 \
        lsum += ls0 + ls1;                                                                \
        o_lo = pv_mfma(p0, v00, o_lo);                                                    \
        o_hi = pv_mfma(p0, v01, o_hi);                                                    \
        o_lo = pv_mfma(p1, v10, o_lo);                                                    \
        o_hi = pv_mfma(p1, v11, o_hi);                                                    \
    } while (0)

#define WAIT4 asm volatile("s_waitcnt vmcnt(4)" ::: "memory")
#define WAIT0 asm volatile("s_waitcnt vmcnt(0)" ::: "memory")
// ds_reads of the buffer about to be re-staged must have EXECUTED before the DMA is issued
// (DMA data can land mid-stall and corrupt pending reads — R13's replay-only race).
#define DSDRAIN asm volatile("s_waitcnt lgkmcnt(0)" ::: "memory")

    STAGE(0, 0);
    STAGE(1, 1);
    for (int c = 0; c < 28; c += 2) {
        WAIT4; COMPUTE(0, c);     DSDRAIN; STAGE(0, c + 2);
        WAIT4; COMPUTE(1, c + 1); DSDRAIN; STAGE(1, c + 3);
    }
    WAIT4; COMPUTE(0, 28); DSDRAIN; STAGE(0, 30);
    WAIT4; COMPUTE(1, 29); DSDRAIN; STAGE(1, 31);
    WAIT4; COMPUTE(0, 30);
    WAIT0; COMPUTE(1, 31);
#undef STAGE
#undef COMPUTE
#undef WAIT4
#undef WAIT0
#undef DSDRAIN

    // lsum on lane = partial row-sum for query l15; finish across quads
    lsum += __shfl_xor(lsum, 16);
    lsum += __shfl_xor(lsum, 32);
#pragma unroll
    for (int r = 0; r < 4; r++) {
        const float inv = 1.f / __shfl(lsum, quad * 4 + r);
        const int i = qbase + quad * 4 + r;
        O[((size_t)(b * 1024 + i) * 256) + h * 32 + l15] = bfbits(o_lo[r] * inv);
        O[((size_t)(b * 1024 + i) * 256) + h * 32 + 16 + l15] = bfbits(o_hi[r] * inv);
    }
}

extern "C" void kernel_launch(void* const* d_in, const int* in_sizes, int n_in,
                              void* d_out, int out_size, void* d_ws, size_t ws_size,
                              hipStream_t stream) {
    const float* x   = (const float*)d_in[0];
    const float* Qw  = (const float*)d_in[1];
    const float* Kw  = (const float*)d_in[2];
    const float* Vw  = (const float*)d_in[3];
    const float* Fw  = (const float*)d_in[4];
    const float* ffb = (const float*)d_in[5];
    const float* RB  = (const float*)d_in[6];
    // d_in[7] = rel_idx (int32): deterministic, computed analytically in-kernel.

    u16* ws = (u16*)d_ws;
    u16* xf = ws;                   // 8192 x 256 bf16 (4 MB)   ... later reused as ob
    u16* wt = xf + 2097152;         // 1024 x 256 bf16 (0.5 MB) [Qw^T|Kw^T|Vw^T|ffw^T]
    u16* q  = wt + 262144;          // (b,h,l,d)  bf16 (4 MB), pre-scaled by log2e
    u16* kk = q  + 2097152;         // (b,h,l,d)  bf16 (4 MB)
    u16* vt = kk + 2097152;         // (b,h,d,l)  bf16 (4 MB)
    float* RBs = (float*)(vt + 2097152);   // 8 x 3969 fp32 (127 KB), bias * log2e
    u16* ob = xf;                   // (b,l,h*32+d) bf16 — aliases xf (dead after V proj)

    prep<<<dim3(608), 256, 0, stream>>>(x, Qw, Kw, Vw, Fw, RB, xf, wt, RBs);
    gemm_fused<<<dim3(1536), 256, 0, stream>>>(xf, wt, q, kk, vt, nullptr, nullptr, nullptr, 0); // QK + V^T
    attn<<<dim3(1024), 256, 0, stream>>>(q, kk, vt, RBs, ob);
    gemm_fused<<<dim3(512), 256, 0, stream>>>(xf, wt, q, kk, vt, ob, (float*)d_out, ffb, 2);     // FF
}

// Round 15
// 118.342 us; speedup vs baseline: 1.1072x; 1.0531x over previous
//
#include <hip/hip_runtime.h>
#include <math.h>

// RelativeAttention on MI355X (gfx950). FP32 inputs/output; bf16 intermediates, fp32 accum.
// Round 15: attn waves process 32 q-rows each (2 Q-tiles per staged K/V chunk) -> compute per
// vmcnt-wait doubles, DMA traffic halves; 512 blocks, __launch_bounds__(256,2). Bias identity
// b1(tileB) == b0(tileA) saves 1 of 4 bias loads. Depth-2 barrier-free pipeline + DSDRAIN
// race fix (R14) retained. GEMMs: async_cp16 + XOR swizzle (R12).
// B=8, C=256, H=W=32 (L=1024), nh=8, dk=dv=32, OUT_C=256.

typedef unsigned short u16;
typedef __bf16 bf16;
typedef bf16 bf16x8 __attribute__((ext_vector_type(8)));
typedef bf16 bf16x4 __attribute__((ext_vector_type(4)));
typedef short s16x4 __attribute__((ext_vector_type(4)));
typedef float f32x4 __attribute__((ext_vector_type(4)));
typedef float f32x4u __attribute__((ext_vector_type(4), aligned(4)));
typedef u16 u16x8 __attribute__((ext_vector_type(8)));
typedef u16 u16x4 __attribute__((ext_vector_type(4)));

#define DEVI __device__ __forceinline__

DEVI u16 bfbits(float f) { return __builtin_bit_cast(u16, (bf16)f); }

DEVI void async_cp16(const u16* g, u16* l) {
    __builtin_amdgcn_global_load_lds((const __attribute__((address_space(1))) void*)g,
                                     (__attribute__((address_space(3))) void*)l, 16, 0, 0);
}

// 16x16x16 bf16 MFMA (K=16): A[m=lane&15][k=quad*4+j], B[k=quad*4+j][n=lane&15],
// C/D[row=quad*4+reg][col=lane&15]. (absmax-verified R7-R14.)
DEVI f32x4 pv_mfma(bf16x4 a, bf16x4 b, f32x4 c) {
#if __has_builtin(__builtin_amdgcn_mfma_f32_16x16x16bf16_1k)
    return __builtin_amdgcn_mfma_f32_16x16x16bf16_1k(
        __builtin_bit_cast(s16x4, a), __builtin_bit_cast(s16x4, b), c, 0, 0, 0);
#else
    asm("s_nop 1\n\tv_mfma_f32_16x16x16_bf16 %0, %1, %2, %0"
        : "+v"(c) : "v"(a), "v"(b));
    return c;
#endif
}

// ---------------- fused prep: transposes + bias prescale ----------------
__global__ __launch_bounds__(256) void prep(const float* __restrict__ X,
                                            const float* __restrict__ Qw, const float* __restrict__ Kw,
                                            const float* __restrict__ Vw, const float* __restrict__ Fw,
                                            const float* __restrict__ RB,
                                            u16* __restrict__ XF, u16* __restrict__ WT,
                                            float* __restrict__ RBs) {
    __shared__ u16 t[64 * 65];
    const int blk = blockIdx.x, tid = threadIdx.x;
    if (blk < 576) {
        const float* src;
        int cbase, rbase, rows_total;
        u16* dst;
        if (blk < 512) {
            const int b = blk >> 6;
            cbase = (blk & 3) * 64; rbase = ((blk >> 2) & 15) * 64;
            src = X + (size_t)b * 256 * 1024; dst = XF + (size_t)b * 1024 * 256;
            rows_total = 1024;
        } else {
            const int t2 = blk - 512, wsel = t2 >> 4;
            cbase = (t2 & 3) * 64; rbase = ((t2 >> 2) & 3) * 64;
            src = wsel == 0 ? Qw : wsel == 1 ? Kw : wsel == 2 ? Vw : Fw;
            dst = WT + (size_t)wsel * 256 * 256;
            rows_total = 256;
        }
        const int w = tid >> 6, r = tid & 63;
#pragma unroll
        for (int i = 0; i < 16; i++) {
            const int c = w * 16 + i;
            t[c * 65 + r] = bfbits(src[(size_t)(cbase + c) * rows_total + rbase + r]);
        }
        __syncthreads();
#pragma unroll
        for (int i = 0; i < 2; i++) {
            const int idx = i * 256 + tid;
            const int r2 = idx >> 3, cg = idx & 7;
            u16x8 v;
#pragma unroll
            for (int j = 0; j < 8; j++) v[j] = t[(cg * 8 + j) * 65 + r2];
            *(u16x8*)&dst[(size_t)(rbase + r2) * 256 + cbase + cg * 8] = v;
        }
    } else {
        const int n = 8 * 3969;
        for (int i = (blk - 576) * 256 + tid; i < n; i += 32 * 256)
            RBs[i] = RB[i] * 1.44269504f;
    }
}

// ---------------- unified GEMM: D[m][n] = sum_k A[m][k]*Bt[n][k], K=256, bf16 in ----------------
// 64x64 tile, BK=32, 4 waves each 32x32. async_cp16 staging + XOR-swizzled chunks.
__global__ __launch_bounds__(256, 6) void gemm_fused(const u16* __restrict__ xf, const u16* __restrict__ wt,
                                                     u16* __restrict__ q, u16* __restrict__ kk,
                                                     u16* __restrict__ vt, const u16* __restrict__ ob,
                                                     float* __restrict__ outf, const float* __restrict__ ffb,
                                                     int base_mode) {
    __shared__ __align__(16) u16 lA[64 * 32];
    __shared__ __align__(16) u16 lB[64 * 32];
    const int tid = threadIdx.x;
    const int wave = tid >> 6, lane = tid & 63;
    const int quad = lane >> 4, l15 = lane & 15;

    int mode, mbase, nbase;
    const u16 *A, *Bt;
    if (base_mode == 2) {
        mode = 2; A = wt + 768 * 256; Bt = ob;               // M=256, N=8192
        mbase = (blockIdx.x & 3) * 64; nbase = (blockIdx.x >> 2) * 64;
    } else if (blockIdx.x < 1024) {
        mode = 0; A = xf; Bt = wt;                            // M=8192, N=512
        mbase = (blockIdx.x >> 3) * 64; nbase = (blockIdx.x & 7) * 64;
    } else {
        mode = 1; A = wt + 512 * 256; Bt = xf;                // M=256, N=8192
        const int t = blockIdx.x - 1024;
        mbase = (t & 3) * 64; nbase = (t >> 2) * 64;
    }

    const int m0 = (wave >> 1) * 32, n0 = (wave & 1) * 32;
    const int srow = tid >> 2;
    const int sgcol = (lane & 3) ^ ((lane >> 3) & 3);
    const size_t arow = (size_t)(mbase + srow) * 256 + sgcol * 8;
    const size_t brow = (size_t)(nbase + srow) * 256 + sgcol * 8;
    const int kcol = ((quad ^ ((l15 >> 1) & 3))) * 8;

    f32x4 acc[2][2];
#pragma unroll
    for (int i = 0; i < 2; i++)
#pragma unroll
        for (int j = 0; j < 2; j++) acc[i][j] = f32x4{0.f, 0.f, 0.f, 0.f};

    for (int kb = 0; kb < 256; kb += 32) {
        __syncthreads();
        async_cp16(&A[arow + kb], &lA[wave * 512]);
        async_cp16(&Bt[brow + kb], &lB[wave * 512]);
        __syncthreads();
        bf16x8 af[2], bfr[2];
#pragma unroll
        for (int i = 0; i < 2; i++) af[i] = *(const bf16x8*)&lA[(m0 + i * 16 + l15) * 32 + kcol];
#pragma unroll
        for (int j = 0; j < 2; j++) bfr[j] = *(const bf16x8*)&lB[(n0 + j * 16 + l15) * 32 + kcol];
#pragma unroll
        for (int i = 0; i < 2; i++)
#pragma unroll
            for (int j = 0; j < 2; j++)
                acc[i][j] = __builtin_amdgcn_mfma_f32_16x16x32_bf16(af[i], bfr[j], acc[i][j], 0, 0, 0);
    }

    // epilogue: C-layout col = lane&15, row = quad*4 + reg
#pragma unroll
    for (int i = 0; i < 2; i++) {
#pragma unroll
        for (int j = 0; j < 2; j++) {
#pragma unroll
            for (int r = 0; r < 4; r++) {
                const int gm = mbase + m0 + i * 16 + quad * 4 + r;
                const int gn = nbase + n0 + j * 16 + l15;
                float v = acc[i][j][r];
                if (mode == 0) {
                    const int b = gm >> 10, l = gm & 1023;
                    int n = gn;
                    u16* dst = q;
                    if (n >= 256) { n -= 256; dst = kk; }
                    else v *= 1.44269504f;                 // fold log2e into q
                    const int h = n >> 5, d = n & 31;
                    dst[(((size_t)(b * 8 + h) * 1024 + l) << 5) + d] = bfbits(v);
                } else if (mode == 1) {
                    const int h = gm >> 5, d = gm & 31;
                    const int b = gn >> 10, l = gn & 1023;
                    vt[(((size_t)(b * 8 + h) * 32 + d) << 10) + l] = bfbits(v);
                } else {
                    const int b = gn >> 10, l = gn & 1023;
                    outf[(((size_t)(b * 256 + gm)) << 10) + l] = v + ffb[gm];
                }
            }
        }
    }
}

// ---------------- flash attention: 2 Q-tiles per wave, barrier-free depth-2 pipeline ----------
// 512 blocks x 4 waves x 32 q-rows. XCD swizzle on blockIdx. Per-wave private K/V LDS
// double-buffers (8 KB), XOR swizzle, STAGE-after-COMPUTE + lgkm drain (R14 race fix).
// Each staged chunk feeds TWO Q-tiles (A: queries qbase..+15, B: +16..+31, same image row):
// 4 QK MFMAs + 16 exp2 + 8 PV MFMAs per chunk — 2x compute per vmcnt wait, half the DMAs.
// Bias identity: tileB's key+16 vector == tileA's key+0 vector (x-shifts cancel).
__global__ __launch_bounds__(256, 2) void attn(const u16* __restrict__ Q, const u16* __restrict__ Kb,
                                               const u16* __restrict__ Vt, const float* __restrict__ RBs,
                                               u16* __restrict__ O) {
    __shared__ __align__(16) u16 kbuf[4][2][32 * 32];   // [wave][buf][key][d], swizzled chunks
    __shared__ __align__(16) u16 vbuf[4][2][32 * 32];   // [wave][buf][d][key], swizzled chunks
    const int tid = threadIdx.x;
    const int wave = tid >> 6, lane = tid & 63;
    const int quad = lane >> 4, l15 = lane & 15;
    const int blk = blockIdx.x;
    const int bh = ((blk >> 6) << 3) + (blk & 7);       // XCD swizzle
    const int qt = (blk >> 3) & 7;
    const int b = bh >> 3, h = bh & 7;
    const int qbase = qt * 128 + wave * 32;             // multiple of 32: one full image row
    const size_t bhL = (size_t)bh * 1024;

    const bf16x8 qfA = *(const bf16x8*)&Q[(bhL + qbase + l15) * 32 + quad * 8];      // queries x=l15
    const bf16x8 qfB = *(const bf16x8*)&Q[(bhL + qbase + 16 + l15) * 32 + quad * 8]; // queries x=16+l15
    // bias idx = (c - yi + 32)*32 + (xj - xi + 32); yi = qbase>>5 (uniform), xiA = l15.
    // tileA: b0A[r]=brow0+c*32+r (keys 0..15), b1A[r]=+16 (keys 16..31).
    // tileB (xi += 16): b0B = brow0+c*32-16+r, b1B = brow0+c*32+r == b0A.
    const float* brow0 = RBs + (size_t)h * 3969
                         + (32 - (qbase >> 5)) * 32 + 32 - l15 + quad * 4;
    const int srow = lane >> 2;
    const int sgcol = (lane & 3) ^ ((lane >> 3) & 3);
    const u16* ksrc = &Kb[bhL * 32];
    const u16* vsrc_lo = &Vt[(((size_t)bh * 32) + srow) << 10];
    const u16* vsrc_hi = &Vt[(((size_t)bh * 32) + 16 + srow) << 10];

    float lsumA = 0.f, lsumB = 0.f;
    f32x4 oA_lo{0.f, 0.f, 0.f, 0.f}, oA_hi{0.f, 0.f, 0.f, 0.f};
    f32x4 oB_lo{0.f, 0.f, 0.f, 0.f}, oB_hi{0.f, 0.f, 0.f, 0.f};

    // reader-side swizzle terms (row-pair XOR)
    const int swz = (l15 >> 1) & 3;
    const int kcol = (quad ^ swz) * 8;
    const int g0 = (2 * ((quad >> 1) ^ swz) + (quad & 1)) * 4;
    const int g1 = (2 * (((quad >> 1) + 2) ^ swz) + (quad & 1)) * 4;

#define STAGE(buf, c) do {                                                              \
        const int kb_ = (c) * 32;                                                       \
        async_cp16(ksrc + kb_ * 32 + srow * 32 + sgcol * 8, &kbuf[wave][buf][0]);       \
        async_cp16(ksrc + kb_ * 32 + 512 + srow * 32 + sgcol * 8, &kbuf[wave][buf][512]); \
        async_cp16(vsrc_lo + kb_ + sgcol * 8, &vbuf[wave][buf][0]);                     \
        async_cp16(vsrc_hi + kb_ + sgcol * 8, &vbuf[wave][buf][512]);                   \
    } while (0)

#define COMPUTE(cur, c) do {                                                              \
        const bf16x8 kf0 = *(const bf16x8*)&kbuf[wave][cur][l15 * 32 + kcol];             \
        const bf16x8 kf1 = *(const bf16x8*)&kbuf[wave][cur][(16 + l15) * 32 + kcol];      \
        const bf16x4 v00 = __builtin_bit_cast(bf16x4, *(const u16x4*)&vbuf[wave][cur][l15 * 32 + g0]); \
        const bf16x4 v10 = __builtin_bit_cast(bf16x4, *(const u16x4*)&vbuf[wave][cur][l15 * 32 + g1]); \
        const bf16x4 v01 = __builtin_bit_cast(bf16x4, *(const u16x4*)&vbuf[wave][cur][(16 + l15) * 32 + g0]); \
        const bf16x4 v11 = __builtin_bit_cast(bf16x4, *(const u16x4*)&vbuf[wave][cur][(16 + l15) * 32 + g1]); \
        const f32x4u bm = *(const f32x4u*)(brow0 + (c) * 32 - 16);                        \
        const f32x4u b0 = *(const f32x4u*)(brow0 + (c) * 32);                             \
        const f32x4u b1 = *(const f32x4u*)(brow0 + (c) * 32 + 16);                        \
        const f32x4 z{0.f, 0.f, 0.f, 0.f};                                                \
        f32x4 s0A = __builtin_amdgcn_mfma_f32_16x16x32_bf16(kf0, qfA, z, 0, 0, 0);        \
        f32x4 s1A = __builtin_amdgcn_mfma_f32_16x16x32_bf16(kf1, qfA, z, 0, 0, 0);        \
        f32x4 s0B = __builtin_amdgcn_mfma_f32_16x16x32_bf16(kf0, qfB, z, 0, 0, 0);        \
        f32x4 s1B = __builtin_amdgcn_mfma_f32_16x16x32_bf16(kf1, qfB, z, 0, 0, 0);        \
        bf16x4 p0A, p1A, p0B, p1B;                                                        \
        float lsA = 0.f, lsB = 0.f;                                                       \
        _Pragma("unroll")                                                                 \
        for (int r = 0; r < 4; r++) {                                                     \
            const float e0A = __builtin_amdgcn_exp2f(s0A[r] + b0[r]);                     \
            const float e1A = __builtin_amdgcn_exp2f(s1A[r] + b1[r]);                     \
            const float e0B = __builtin_amdgcn_exp2f(s0B[r] + bm[r]);                     \
            const float e1B = __builtin_amdgcn_exp2f(s1B[r] + b0[r]);                     \
            lsA += e0A + e1A; lsB += e0B + e1B;                                           \
            p0A[r] = (bf16)e0A; p1A[r] = (bf16)e1A;                                       \
            p0B[r] = (bf16)e0B; p1B[r] = (bf16)e1B;                                       \
        }                                                                                 \
        lsumA += lsA; lsumB += lsB;                                                       \
        oA_lo = pv_mfma(p0A, v00, oA_lo);                                                 \
        oA_hi = pv_mfma(p0A, v01, oA_hi);                                                 \
        oA_lo = pv_mfma(p1A, v10, oA_lo);                                                 \
        oA_hi = pv_mfma(p1A, v11, oA_hi);                                                 \
        oB_lo = pv_mfma(p0B, v00, oB_lo);                                                 \
        oB_hi = pv_mfma(p0B, v01, oB_hi);                                                 \
        oB_lo = pv_mfma(p1B, v10, oB_lo);                                                 \
        oB_hi = pv_mfma(p1B, v11, oB_hi);                                                 \
    } while (0)

#define WAIT4 asm volatile("s_waitcnt vmcnt(4)" ::: "memory")
#define WAIT0 asm volatile("s_waitcnt vmcnt(0)" ::: "memory")
// ds_reads of the buffer about to be re-staged must have EXECUTED before the DMA is issued.
#define DSDRAIN asm volatile("s_waitcnt lgkmcnt(0)" ::: "memory")

    STAGE(0, 0);
    STAGE(1, 1);
    for (int c = 0; c < 28; c += 2) {
        WAIT4; COMPUTE(0, c);     DSDRAIN; STAGE(0, c + 2);
        WAIT4; COMPUTE(1, c + 1); DSDRAIN; STAGE(1, c + 3);
    }
    WAIT4; COMPUTE(0, 28); DSDRAIN; STAGE(0, 30);
    WAIT4; COMPUTE(1, 29); DSDRAIN; STAGE(1, 31);
    WAIT4; COMPUTE(0, 30);
    WAIT0; COMPUTE(1, 31);
#undef STAGE
#undef COMPUTE
#undef WAIT4
#undef WAIT0
#undef DSDRAIN

    // per-lane lsum = partial row-sum for its query; finish across quads
    lsumA += __shfl_xor(lsumA, 16);
    lsumA += __shfl_xor(lsumA, 32);
    lsumB += __shfl_xor(lsumB, 16);
    lsumB += __shfl_xor(lsumB, 32);
#pragma unroll
    for (int r = 0; r < 4; r++) {
        const float invA = 1.f / __shfl(lsumA, quad * 4 + r);
        const float invB = 1.f / __shfl(lsumB, quad * 4 + r);
        const int iA = qbase + quad * 4 + r;
        const int iB = iA + 16;
        O[((size_t)(b * 1024 + iA) * 256) + h * 32 + l15] = bfbits(oA_lo[r] * invA);
        O[((size_t)(b * 1024 + iA) * 256) + h * 32 + 16 + l15] = bfbits(oA_hi[r] * invA);
        O[((size_t)(b * 1024 + iB) * 256) + h * 32 + l15] = bfbits(oB_lo[r] * invB);
        O[((size_t)(b * 1024 + iB) * 256) + h * 32 + 16 + l15] = bfbits(oB_hi[r] * invB);
    }
}

extern "C" void kernel_launch(void* const* d_in, const int* in_sizes, int n_in,
                              void* d_out, int out_size, void* d_ws, size_t ws_size,
                              hipStream_t stream) {
    const float* x   = (const float*)d_in[0];
    const float* Qw  = (const float*)d_in[1];
    const float* Kw  = (const float*)d_in[2];
    const float* Vw  = (const float*)d_in[3];
    const float* Fw  = (const float*)d_in[4];
    const float* ffb = (const float*)d_in[5];
    const float* RB  = (const float*)d_in[6];
    // d_in[7] = rel_idx (int32): deterministic, computed analytically in-kernel.

    u16* ws = (u16*)d_ws;
    u16* xf = ws;                   // 8192 x 256 bf16 (4 MB)   ... later reused as ob
    u16* wt = xf + 2097152;         // 1024 x 256 bf16 (0.5 MB) [Qw^T|Kw^T|Vw^T|ffw^T]
    u16* q  = wt + 262144;          // (b,h,l,d)  bf16 (4 MB), pre-scaled by log2e
    u16* kk = q  + 2097152;         // (b,h,l,d)  bf16 (4 MB)
    u16* vt = kk + 2097152;         // (b,h,d,l)  bf16 (4 MB)
    float* RBs = (float*)(vt + 2097152);   // 8 x 3969 fp32 (127 KB), bias * log2e
    u16* ob = xf;                   // (b,l,h*32+d) bf16 — aliases xf (dead after V proj)

    prep<<<dim3(608), 256, 0, stream>>>(x, Qw, Kw, Vw, Fw, RB, xf, wt, RBs);
    gemm_fused<<<dim3(1536), 256, 0, stream>>>(xf, wt, q, kk, vt, nullptr, nullptr, nullptr, 0); // QK + V^T
    attn<<<dim3(512), 256, 0, stream>>>(q, kk, vt, RBs, ob);
    gemm_fused<<<dim3(512), 256, 0, stream>>>(xf, wt, q, kk, vt, ob, (float*)d_out, ffb, 2);     // FF
}

// Round 16
// 117.846 us; speedup vs baseline: 1.1118x; 1.0042x over previous
//
#include <hip/hip_runtime.h>
#include <math.h>

// RelativeAttention on MI355X (gfx950). FP32 inputs/output; bf16 intermediates, fp32 accum.
// Round 16: proj GEMM re-tiled 128x64 (wave=64x32, 8 MFMA per K-tile per wave, 768 blocks =
// 3/CU) — doubles barrier/DMA amortization; FF stays 64x64 (occupancy-bound). attn = R15
// (2 Q-tiles per staged chunk, barrier-free depth-2 pipeline, DSDRAIN race fix).
// B=8, C=256, H=W=32 (L=1024), nh=8, dk=dv=32, OUT_C=256.

typedef unsigned short u16;
typedef __bf16 bf16;
typedef bf16 bf16x8 __attribute__((ext_vector_type(8)));
typedef bf16 bf16x4 __attribute__((ext_vector_type(4)));
typedef short s16x4 __attribute__((ext_vector_type(4)));
typedef float f32x4 __attribute__((ext_vector_type(4)));
typedef float f32x4u __attribute__((ext_vector_type(4), aligned(4)));
typedef u16 u16x8 __attribute__((ext_vector_type(8)));
typedef u16 u16x4 __attribute__((ext_vector_type(4)));

#define DEVI __device__ __forceinline__

DEVI u16 bfbits(float f) { return __builtin_bit_cast(u16, (bf16)f); }

DEVI void async_cp16(const u16* g, u16* l) {
    __builtin_amdgcn_global_load_lds((const __attribute__((address_space(1))) void*)g,
                                     (__attribute__((address_space(3))) void*)l, 16, 0, 0);
}

// 16x16x16 bf16 MFMA (K=16): A[m=lane&15][k=quad*4+j], B[k=quad*4+j][n=lane&15],
// C/D[row=quad*4+reg][col=lane&15]. (absmax-verified R7-R15.)
DEVI f32x4 pv_mfma(bf16x4 a, bf16x4 b, f32x4 c) {
#if __has_builtin(__builtin_amdgcn_mfma_f32_16x16x16bf16_1k)
    return __builtin_amdgcn_mfma_f32_16x16x16bf16_1k(
        __builtin_bit_cast(s16x4, a), __builtin_bit_cast(s16x4, b), c, 0, 0, 0);
#else
    asm("s_nop 1\n\tv_mfma_f32_16x16x16_bf16 %0, %1, %2, %0"
        : "+v"(c) : "v"(a), "v"(b));
    return c;
#endif
}

// ---------------- fused prep: transposes + bias prescale ----------------
__global__ __launch_bounds__(256) void prep(const float* __restrict__ X,
                                            const float* __restrict__ Qw, const float* __restrict__ Kw,
                                            const float* __restrict__ Vw, const float* __restrict__ Fw,
                                            const float* __restrict__ RB,
                                            u16* __restrict__ XF, u16* __restrict__ WT,
                                            float* __restrict__ RBs) {
    __shared__ u16 t[64 * 65];
    const int blk = blockIdx.x, tid = threadIdx.x;
    if (blk < 576) {
        const float* src;
        int cbase, rbase, rows_total;
        u16* dst;
        if (blk < 512) {
            const int b = blk >> 6;
            cbase = (blk & 3) * 64; rbase = ((blk >> 2) & 15) * 64;
            src = X + (size_t)b * 256 * 1024; dst = XF + (size_t)b * 1024 * 256;
            rows_total = 1024;
        } else {
            const int t2 = blk - 512, wsel = t2 >> 4;
            cbase = (t2 & 3) * 64; rbase = ((t2 >> 2) & 3) * 64;
            src = wsel == 0 ? Qw : wsel == 1 ? Kw : wsel == 2 ? Vw : Fw;
            dst = WT + (size_t)wsel * 256 * 256;
            rows_total = 256;
        }
        const int w = tid >> 6, r = tid & 63;
#pragma unroll
        for (int i = 0; i < 16; i++) {
            const int c = w * 16 + i;
            t[c * 65 + r] = bfbits(src[(size_t)(cbase + c) * rows_total + rbase + r]);
        }
        __syncthreads();
#pragma unroll
        for (int i = 0; i < 2; i++) {
            const int idx = i * 256 + tid;
            const int r2 = idx >> 3, cg = idx & 7;
            u16x8 v;
#pragma unroll
            for (int j = 0; j < 8; j++) v[j] = t[(cg * 8 + j) * 65 + r2];
            *(u16x8*)&dst[(size_t)(rbase + r2) * 256 + cbase + cg * 8] = v;
        }
    } else {
        const int n = 8 * 3969;
        for (int i = (blk - 576) * 256 + tid; i < n; i += 32 * 256)
            RBs[i] = RB[i] * 1.44269504f;
    }
}

// ---------------- unified GEMM: D[m][n] = sum_k A[m][k]*Bt[n][k], K=256, bf16 in ----------------
// Tile (MFR*32) x 64, BK=32; 4 waves as 2x2, wave = (MFR*16) x 32. async_cp16 staging +
// XOR-swizzled chunks (swizzle formulas are 64-row-period invariant).
// PASS 0: blocks 0..511 mode 0 (xf*wt -> q,k), 512..767 mode 1 (Vw^T*xf -> v^T). MFR=4.
// PASS 2: FF (ffw^T*ob -> fp32 out + bias). MFR=2, 512 blocks.
template <int MFR, int PASS>
__global__ __launch_bounds__(256, 3) void gemm_fused(const u16* __restrict__ xf, const u16* __restrict__ wt,
                                                     u16* __restrict__ q, u16* __restrict__ kk,
                                                     u16* __restrict__ vt, const u16* __restrict__ ob,
                                                     float* __restrict__ outf, const float* __restrict__ ffb) {
    constexpr int TM = MFR * 32;                       // block M-span
    __shared__ __align__(16) u16 lA[TM * 32];
    __shared__ __align__(16) u16 lB[64 * 32];
    const int tid = threadIdx.x;
    const int wave = tid >> 6, lane = tid & 63;
    const int quad = lane >> 4, l15 = lane & 15;

    int mode, mbase, nbase;
    const u16 *A, *Bt;
    if (PASS == 2) {
        mode = 2; A = wt + 768 * 256; Bt = ob;               // M=256, N=8192
        mbase = (blockIdx.x & 3) * 64; nbase = (blockIdx.x >> 2) * 64;
    } else if (blockIdx.x < 512) {
        mode = 0; A = xf; Bt = wt;                            // M=8192, N=512
        mbase = (blockIdx.x >> 3) * TM; nbase = (blockIdx.x & 7) * 64;
    } else {
        mode = 1; A = wt + 512 * 256; Bt = xf;                // M=256, N=8192
        const int t = blockIdx.x - 512;
        mbase = (t & 1) * TM; nbase = (t >> 1) * 64;
    }

    const int m0 = (wave >> 1) * (MFR * 16), n0 = (wave & 1) * 32;
    const int srow = tid >> 2;                         // wave*16 + lane>>2: rows per 64-row half
    const int sgcol = (lane & 3) ^ ((lane >> 3) & 3);  // swizzled global chunk col (64-row invariant)
    const int kcol = ((quad ^ ((l15 >> 1) & 3))) * 8;  // reader chunk (16-row-base invariant)

    f32x4 acc[MFR][2];
#pragma unroll
    for (int i = 0; i < MFR; i++)
#pragma unroll
        for (int j = 0; j < 2; j++) acc[i][j] = f32x4{0.f, 0.f, 0.f, 0.f};

    for (int kb = 0; kb < 256; kb += 32) {
        __syncthreads();
#pragma unroll
        for (int half = 0; half < MFR / 2; half++)     // A: one DMA per 64-row half
            async_cp16(&A[(size_t)(mbase + half * 64 + srow) * 256 + kb + sgcol * 8],
                       &lA[half * 2048 + wave * 512]);
        async_cp16(&Bt[(size_t)(nbase + srow) * 256 + kb + sgcol * 8], &lB[wave * 512]);
        __syncthreads();
        bf16x8 af[MFR], bfr[2];
#pragma unroll
        for (int i = 0; i < MFR; i++) af[i] = *(const bf16x8*)&lA[(m0 + i * 16 + l15) * 32 + kcol];
#pragma unroll
        for (int j = 0; j < 2; j++) bfr[j] = *(const bf16x8*)&lB[(n0 + j * 16 + l15) * 32 + kcol];
#pragma unroll
        for (int i = 0; i < MFR; i++)
#pragma unroll
            for (int j = 0; j < 2; j++)
                acc[i][j] = __builtin_amdgcn_mfma_f32_16x16x32_bf16(af[i], bfr[j], acc[i][j], 0, 0, 0);
    }

    // epilogue: C-layout col = lane&15, row = quad*4 + reg
#pragma unroll
    for (int i = 0; i < MFR; i++) {
#pragma unroll
        for (int j = 0; j < 2; j++) {
#pragma unroll
            for (int r = 0; r < 4; r++) {
                const int gm = mbase + m0 + i * 16 + quad * 4 + r;
                const int gn = nbase + n0 + j * 16 + l15;
                float v = acc[i][j][r];
                if (mode == 0) {
                    const int b = gm >> 10, l = gm & 1023;
                    int n = gn;
                    u16* dst = q;
                    if (n >= 256) { n -= 256; dst = kk; }
                    else v *= 1.44269504f;                 // fold log2e into q
                    const int h = n >> 5, d = n & 31;
                    dst[(((size_t)(b * 8 + h) * 1024 + l) << 5) + d] = bfbits(v);
                } else if (mode == 1) {
                    const int h = gm >> 5, d = gm & 31;
                    const int b = gn >> 10, l = gn & 1023;
                    vt[(((size_t)(b * 8 + h) * 32 + d) << 10) + l] = bfbits(v);
                } else {
                    const int b = gn >> 10, l = gn & 1023;
                    outf[(((size_t)(b * 256 + gm)) << 10) + l] = v + ffb[gm];
                }
            }
        }
    }
}

// ---------------- flash attention: 2 Q-tiles per wave, barrier-free depth-2 pipeline ----------
// 512 blocks x 4 waves x 32 q-rows (R15, unchanged). Per-wave private K/V LDS double-buffers,
// XOR swizzle, STAGE-after-COMPUTE + lgkm drain. Bias identity b1(tileB)==b0(tileA).
__global__ __launch_bounds__(256, 2) void attn(const u16* __restrict__ Q, const u16* __restrict__ Kb,
                                               const u16* __restrict__ Vt, const float* __restrict__ RBs,
                                               u16* __restrict__ O) {
    __shared__ __align__(16) u16 kbuf[4][2][32 * 32];
    __shared__ __align__(16) u16 vbuf[4][2][32 * 32];
    const int tid = threadIdx.x;
    const int wave = tid >> 6, lane = tid & 63;
    const int quad = lane >> 4, l15 = lane & 15;
    const int blk = blockIdx.x;
    const int bh = ((blk >> 6) << 3) + (blk & 7);       // XCD swizzle
    const int qt = (blk >> 3) & 7;
    const int b = bh >> 3, h = bh & 7;
    const int qbase = qt * 128 + wave * 32;
    const size_t bhL = (size_t)bh * 1024;

    const bf16x8 qfA = *(const bf16x8*)&Q[(bhL + qbase + l15) * 32 + quad * 8];
    const bf16x8 qfB = *(const bf16x8*)&Q[(bhL + qbase + 16 + l15) * 32 + quad * 8];
    const float* brow0 = RBs + (size_t)h * 3969
                         + (32 - (qbase >> 5)) * 32 + 32 - l15 + quad * 4;
    const int srow = lane >> 2;
    const int sgcol = (lane & 3) ^ ((lane >> 3) & 3);
    const u16* ksrc = &Kb[bhL * 32];
    const u16* vsrc_lo = &Vt[(((size_t)bh * 32) + srow) << 10];
    const u16* vsrc_hi = &Vt[(((size_t)bh * 32) + 16 + srow) << 10];

    float lsumA = 0.f, lsumB = 0.f;
    f32x4 oA_lo{0.f, 0.f, 0.f, 0.f}, oA_hi{0.f, 0.f, 0.f, 0.f};
    f32x4 oB_lo{0.f, 0.f, 0.f, 0.f}, oB_hi{0.f, 0.f, 0.f, 0.f};

    const int swz = (l15 >> 1) & 3;
    const int kcol = (quad ^ swz) * 8;
    const int g0 = (2 * ((quad >> 1) ^ swz) + (quad & 1)) * 4;
    const int g1 = (2 * (((quad >> 1) + 2) ^ swz) + (quad & 1)) * 4;

#define STAGE(buf, c) do {                                                              \
        const int kb_ = (c) * 32;                                                       \
        async_cp16(ksrc + kb_ * 32 + srow * 32 + sgcol * 8, &kbuf[wave][buf][0]);       \
        async_cp16(ksrc + kb_ * 32 + 512 + srow * 32 + sgcol * 8, &kbuf[wave][buf][512]); \
        async_cp16(vsrc_lo + kb_ + sgcol * 8, &vbuf[wave][buf][0]);                     \
        async_cp16(vsrc_hi + kb_ + sgcol * 8, &vbuf[wave][buf][512]);                   \
    } while (0)

#define COMPUTE(cur, c) do {                                                              \
        const bf16x8 kf0 = *(const bf16x8*)&kbuf[wave][cur][l15 * 32 + kcol];             \
        const bf16x8 kf1 = *(const bf16x8*)&kbuf[wave][cur][(16 + l15) * 32 + kcol];      \
        const bf16x4 v00 = __builtin_bit_cast(bf16x4, *(const u16x4*)&vbuf[wave][cur][l15 * 32 + g0]); \
        const bf16x4 v10 = __builtin_bit_cast(bf16x4, *(const u16x4*)&vbuf[wave][cur][l15 * 32 + g1]); \
        const bf16x4 v01 = __builtin_bit_cast(bf16x4, *(const u16x4*)&vbuf[wave][cur][(16 + l15) * 32 + g0]); \
        const bf16x4 v11 = __builtin_bit_cast(bf16x4, *(const u16x4*)&vbuf[wave][cur][(16 + l15) * 32 + g1]); \
        const f32x4u bm = *(const f32x4u*)(brow0 + (c) * 32 - 16);                        \
        const f32x4u b0 = *(const f32x4u*)(brow0 + (c) * 32);                             \
        const f32x4u b1 = *(const f32x4u*)(brow0 + (c) * 32 + 16);                        \
        const f32x4 z{0.f, 0.f, 0.f, 0.f};                                                \
        f32x4 s0A = __builtin_amdgcn_mfma_f32_16x16x32_bf16(kf0, qfA, z, 0, 0, 0);        \
        f32x4 s1A = __builtin_amdgcn_mfma_f32_16x16x32_bf16(kf1, qfA, z, 0, 0, 0);        \
        f32x4 s0B = __builtin_amdgcn_mfma_f32_16x16x32_bf16(kf0, qfB, z, 0, 0, 0);        \
        f32x4 s1B = __builtin_amdgcn_mfma_f32_16x16x32_bf16(kf1, qfB, z, 0, 0, 0);        \
        bf16x4 p0A, p1A, p0B, p1B;                                                        \
        float lsA = 0.f, lsB = 0.f;                                                       \
        _Pragma("unroll")                                                                 \
        for (int r = 0; r < 4; r++) {                                                     \
            const float e0A = __builtin_amdgcn_exp2f(s0A[r] + b0[r]);                     \
            const float e1A = __builtin_amdgcn_exp2f(s1A[r] + b1[r]);                     \
            const float e0B = __builtin_amdgcn_exp2f(s0B[r] + bm[r]);                     \
            const float e1B = __builtin_amdgcn_exp2f(s1B[r] + b0[r]);                     \
            lsA += e0A + e1A; lsB += e0B + e1B;                                           \
            p0A[r] = (bf16)e0A; p1A[r] = (bf16)e1A;                                       \
            p0B[r] = (bf16)e0B; p1B[r] = (bf16)e1B;                                       \
        }                                                                                 \
        lsumA += lsA; lsumB += lsB;                                                       \
        oA_lo = pv_mfma(p0A, v00, oA_lo);                                                 \
        oA_hi = pv_mfma(p0A, v01, oA_hi);                                                 \
        oA_lo = pv_mfma(p1A, v10, oA_lo);                                                 \
        oA_hi = pv_mfma(p1A, v11, oA_hi);                                                 \
        oB_lo = pv_mfma(p0B, v00, oB_lo);                                                 \
        oB_hi = pv_mfma(p0B, v01, oB_hi);                                                 \
        oB_lo = pv_mfma(p1B, v10, oB_lo);                                                 \
        oB_hi = pv_mfma(p1B, v11, oB_hi);                                                 \
    } while (0)

#define WAIT4 asm volatile("s_waitcnt vmcnt(4)" ::: "memory")
#define WAIT0 asm volatile("s_waitcnt vmcnt(0)" ::: "memory")
#define DSDRAIN asm volatile("s_waitcnt lgkmcnt(0)" ::: "memory")

    STAGE(0, 0);
    STAGE(1, 1);
    for (int c = 0; c < 28; c += 2) {
        WAIT4; COMPUTE(0, c);     DSDRAIN; STAGE(0, c + 2);
        WAIT4; COMPUTE(1, c + 1); DSDRAIN; STAGE(1, c + 3);
    }
    WAIT4; COMPUTE(0, 28); DSDRAIN; STAGE(0, 30);
    WAIT4; COMPUTE(1, 29); DSDRAIN; STAGE(1, 31);
    WAIT4; COMPUTE(0, 30);
    WAIT0; COMPUTE(1, 31);
#undef STAGE
#undef COMPUTE
#undef WAIT4
#undef WAIT0
#undef DSDRAIN

    lsumA += __shfl_xor(lsumA, 16);
    lsumA += __shfl_xor(lsumA, 32);
    lsumB += __shfl_xor(lsumB, 16);
    lsumB += __shfl_xor(lsumB, 32);
#pragma unroll
    for (int r = 0; r < 4; r++) {
        const float invA = 1.f / __shfl(lsumA, quad * 4 + r);
        const float invB = 1.f / __shfl(lsumB, quad * 4 + r);
        const int iA = qbase + quad * 4 + r;
        const int iB = iA + 16;
        O[((size_t)(b * 1024 + iA) * 256) + h * 32 + l15] = bfbits(oA_lo[r] * invA);
        O[((size_t)(b * 1024 + iA) * 256) + h * 32 + 16 + l15] = bfbits(oA_hi[r] * invA);
        O[((size_t)(b * 1024 + iB) * 256) + h * 32 + l15] = bfbits(oB_lo[r] * invB);
        O[((size_t)(b * 1024 + iB) * 256) + h * 32 + 16 + l15] = bfbits(oB_hi[r] * invB);
    }
}

extern "C" void kernel_launch(void* const* d_in, const int* in_sizes, int n_in,
                              void* d_out, int out_size, void* d_ws, size_t ws_size,
                              hipStream_t stream) {
    const float* x   = (const float*)d_in[0];
    const float* Qw  = (const float*)d_in[1];
    const float* Kw  = (const float*)d_in[2];
    const float* Vw  = (const float*)d_in[3];
    const float* Fw  = (const float*)d_in[4];
    const float* ffb = (const float*)d_in[5];
    const float* RB  = (const float*)d_in[6];
    // d_in[7] = rel_idx (int32): deterministic, computed analytically in-kernel.

    u16* ws = (u16*)d_ws;
    u16* xf = ws;                   // 8192 x 256 bf16 (4 MB)   ... later reused as ob
    u16* wt = xf + 2097152;         // 1024 x 256 bf16 (0.5 MB) [Qw^T|Kw^T|Vw^T|ffw^T]
    u16* q  = wt + 262144;          // (b,h,l,d)  bf16 (4 MB), pre-scaled by log2e
    u16* kk = q  + 2097152;         // (b,h,l,d)  bf16 (4 MB)
    u16* vt = kk + 2097152;         // (b,h,d,l)  bf16 (4 MB)
    float* RBs = (float*)(vt + 2097152);   // 8 x 3969 fp32 (127 KB), bias * log2e
    u16* ob = xf;                   // (b,l,h*32+d) bf16 — aliases xf (dead after V proj)

    prep<<<dim3(608), 256, 0, stream>>>(x, Qw, Kw, Vw, Fw, RB, xf, wt, RBs);
    gemm_fused<4, 0><<<dim3(768), 256, 0, stream>>>(xf, wt, q, kk, vt, nullptr, nullptr, nullptr); // QK + V^T
    attn<<<dim3(512), 256, 0, stream>>>(q, kk, vt, RBs, ob);
    gemm_fused<2, 2><<<dim3(512), 256, 0, stream>>>(xf, wt, q, kk, vt, ob, (float*)d_out, ffb);    // FF
}